// Round 12
// baseline (419415.967 us; speedup 1.0000x reference)
//
#include <hip/hip_runtime.h>
#include <math.h>

#define T_STEPS 65536
#define HID     512
#define NACT    64     // cohort size (one XCD, runtime-verified via election)
#define NLAUNCH 512    // pigeonhole: some XCD fills 64 slots
#define WGSIZE  256

typedef float f4v __attribute__((ext_vector_type(4)));
typedef float f2v __attribute__((ext_vector_type(2)));

// R12: XCD-local mailbox via atomics-execute-at-L2.
//  - R3's proven cohort election (agent scope) picks 64 WGs on ONE XCD.
//  - Posts:  workgroup-scope atomic_exchange (sc1=0 -> executes at local L2;
//            result consumed by asm so LLVM can't demote xchg -> store).
//  - Polls:  workgroup-scope fetch_add(+laundered 0) -> RMW at the SAME L2.
//            Symmetric scope => producer/consumer meet at the same cache =>
//            liveness by construction. Every-64-spins agent-scope fallback
//            covers the "workgroup RMW lands at LIC" world (degrades to ~R2,
//            never hangs; exact tag match keeps correctness always).
//  - Rest = R11 skeleton: 1 barrier/step, 2-deep x reg prefetch, pinned
//            weights, 4-acc dot, exp2/rcp gates, ds_swizzle gathers.
// Layout per WG: slot owns 8 h-indices [slot*8, slot*8+8).
//   lane = r + 8*g: r -> (jloc=r&1, gate=r>>1) (PyTorch i,f,g,o), g = k-group.

__global__ __launch_bounds__(WGSIZE, 1)
void lstm_l2rmw(const float* __restrict__ x,      // [T,512]
                const float* __restrict__ Wih,    // [2048,512]
                const float* __restrict__ Whh,    // [2048,512]
                const float* __restrict__ bih,    // [2048]
                const float* __restrict__ bhh,    // [2048]
                float* __restrict__ out,          // [512]
                unsigned long long* hbuf,         // [2][512] tagged pairs
                int* elect)                       // [8] ctrs + [1] winner
{
  const int tid = threadIdx.x;

  // ---- XCD cohort election (one-time, agent scope; proven R3-R6) ----
  __shared__ int s_slot;
  if (tid == 0) {
    int xcd;
    asm volatile("s_getreg_b32 %0, hwreg(HW_REG_XCC_ID)" : "=s"(xcd));
    int slot = __hip_atomic_fetch_add(&elect[xcd], 1, __ATOMIC_RELAXED,
                                      __HIP_MEMORY_SCOPE_AGENT);
    if (slot == NACT - 1) {
      int exp0 = 0;
      __hip_atomic_compare_exchange_strong(&elect[8], &exp0, xcd + 1,
          __ATOMIC_RELEASE, __ATOMIC_RELAXED, __HIP_MEMORY_SCOPE_AGENT);
    }
    int w;
    do {
      w = __hip_atomic_load(&elect[8], __ATOMIC_ACQUIRE, __HIP_MEMORY_SCOPE_AGENT);
      if (w == 0) __builtin_amdgcn_s_sleep(2);
    } while (w == 0);
    s_slot = (xcd == w - 1 && slot < NACT) ? slot : -1;
  }
  __syncthreads();
  const int slot = s_slot;
  if (slot < 0) return;   // not in winning cohort

  const int wid  = tid >> 6;
  const int lane = tid & 63;
  const int r    = lane & 7;
  const int g    = lane >> 3;
  const int k0   = g << 6;
  const int jloc = r & 1;
  const int gate = r >> 1;            // 0=i 1=f 2=g 3=o
  const int hidx = slot * 8 + wid * 2 + jloc;
  const int row  = gate * HID + hidx;

  __shared__ __align__(16) float hl[2][512];
  __shared__ __align__(16) float xl[2][512];

  // ---- weights into registers ----
  float whh[64], wih[64];
#pragma unroll
  for (int i = 0; i < 16; ++i) {
    const int kk = k0 + (((i + g) & 15) << 2);
    float4 a = *reinterpret_cast<const float4*>(Whh + (size_t)row * 512 + kk);
    float4 b = *reinterpret_cast<const float4*>(Wih + (size_t)row * 512 + kk);
    whh[4*i+0] = a.x; whh[4*i+1] = a.y; whh[4*i+2] = a.z; whh[4*i+3] = a.w;
    wih[4*i+0] = b.x; wih[4*i+1] = b.y; wih[4*i+2] = b.z; wih[4*i+3] = b.w;
  }
  float bias = bih[row] + bhh[row];
#pragma unroll
  for (int i = 0; i < 64; ++i) {
    asm volatile("" : "+v"(whh[i]));
    asm volatile("" : "+v"(wih[i]));
  }
  asm volatile("" : "+v"(bias));

  // laundered zero: keeps fetch_add(+0) a real RMW (no fold-to-load)
  unsigned long long z0 = 0;
  asm volatile("" : "+v"(z0));

  // ---- stage x_0; prefetch x_1 ----
  if (tid < 128) {
    f4v v = *(reinterpret_cast<const f4v*>(x) + tid);
    *reinterpret_cast<f4v*>(&xl[0][tid * 4]) = v;
  }
  f4v xv;
  if (tid < 128)
    xv = __builtin_nontemporal_load(reinterpret_cast<const f4v*>(x + 512) + tid);
  __syncthreads();

  auto dot_lds = [&](const float* lds, const float* w) -> float {
    float a0 = 0.f, a1 = 0.f, a2 = 0.f, a3 = 0.f;
#pragma unroll
    for (int i = 0; i < 16; ++i) {
      const int kk = k0 + (((i + g) & 15) << 2);
      float4 v = *reinterpret_cast<const float4*>(lds + kk);
      a0 = fmaf(w[4*i+0], v.x, a0);
      a1 = fmaf(w[4*i+1], v.y, a1);
      a2 = fmaf(w[4*i+2], v.z, a2);
      a3 = fmaf(w[4*i+3], v.w, a3);
    }
    return (a0 + a1) + (a2 + a3);
  };

  const float LOG2E  = 1.4426950408889634f;
  const float LOG2E2 = 2.8853900817779268f;

  float xacc = dot_lds(xl[0], wih);
  float c    = 0.f;

#pragma unroll 1
  for (int t = 0; t < T_STEPS; ++t) {
    // ======== staging ========
    if (t > 0) {
      unsigned long long* src = hbuf + (((t - 1) & 1) << 9) + (tid << 1);
      const unsigned exp = (unsigned)t;
      unsigned long long p0, p1;
      int spins = 0;
      while (true) {
        p0 = __hip_atomic_fetch_add(src + 0, z0, __ATOMIC_RELAXED,
                                    __HIP_MEMORY_SCOPE_WORKGROUP);
        p1 = __hip_atomic_fetch_add(src + 1, z0, __ATOMIC_RELAXED,
                                    __HIP_MEMORY_SCOPE_WORKGROUP);
        if ((unsigned)(p0 >> 32) == exp && (unsigned)(p1 >> 32) == exp) break;
        if ((++spins & 63) == 0) {   // liveness fallback: LIC-level RMW
          p0 = __hip_atomic_fetch_add(src + 0, z0, __ATOMIC_RELAXED,
                                      __HIP_MEMORY_SCOPE_AGENT);
          p1 = __hip_atomic_fetch_add(src + 1, z0, __ATOMIC_RELAXED,
                                      __HIP_MEMORY_SCOPE_AGENT);
          if ((unsigned)(p0 >> 32) == exp && (unsigned)(p1 >> 32) == exp) break;
        }
      }
      f2v hv;
      hv.x = __uint_as_float((unsigned)p0);
      hv.y = __uint_as_float((unsigned)p1);
      *reinterpret_cast<f2v*>(&hl[t & 1][tid << 1]) = hv;
    }
    if ((tid < 128) && (t + 1 < T_STEPS))
      *reinterpret_cast<f4v*>(&xl[(t + 1) & 1][tid * 4]) = xv;
    __syncthreads();   // single barrier per step

    // ======== compute ========
    if ((tid < 128) && (t + 2 < T_STEPS))
      xv = __builtin_nontemporal_load(
          reinterpret_cast<const f4v*>(x + (size_t)(t + 2) * 512) + tid);

    float acc = xacc;
    if (t > 0) acc += dot_lds(hl[t & 1], whh);
    acc += __int_as_float(__builtin_amdgcn_ds_swizzle(__float_as_int(acc), 0x201F));
    acc += __int_as_float(__builtin_amdgcn_ds_swizzle(__float_as_int(acc), 0x401F));
    acc += __shfl_xor(acc, 32);
    acc += bias;

    const bool isg = (gate == 2);
    float xs = isg ? 2.f * acc : acc;
    float s  = __builtin_amdgcn_rcpf(1.f + exp2f(-xs * LOG2E));
    float v  = isg ? (2.f * s - 1.f) : s;

    const int vb = __float_as_int(v);
    float iv = __int_as_float(__builtin_amdgcn_ds_swizzle(vb, 0x019));
    float fv = __int_as_float(__builtin_amdgcn_ds_swizzle(vb, 0x059));
    float gv = __int_as_float(__builtin_amdgcn_ds_swizzle(vb, 0x099));
    float ov = __int_as_float(__builtin_amdgcn_ds_swizzle(vb, 0x0D9));

    c = fv * c + iv * gv;
    float th = 2.f * __builtin_amdgcn_rcpf(1.f + exp2f(-LOG2E2 * c)) - 1.f;
    float hn = ov * th;

    // post h_t: workgroup-scope exchange -> RMW at local L2 (result consumed
    // so the xchg can't be demoted to a store)
    if (lane < 2) {
      unsigned long long pk =
          ((unsigned long long)(unsigned)(t + 1) << 32) | (unsigned)__float_as_uint(hn);
      unsigned long long old = __hip_atomic_exchange(
          hbuf + ((t & 1) << 9) + slot * 8 + wid * 2 + lane, pk,
          __ATOMIC_RELAXED, __HIP_MEMORY_SCOPE_WORKGROUP);
      asm volatile("" :: "v"(old));
    }

    // x-projection partial for t+1 (off critical path)
    if (t + 1 < T_STEPS) xacc = dot_lds(xl[(t + 1) & 1], wih);
  }

  // ---- softmax(h_{T-1}) by slot 0, wave 0 ----
  if (slot == 0 && wid == 0) {
    unsigned long long* src = hbuf + (((T_STEPS - 1) & 1) << 9);
    float hv[8];
    {
      unsigned long long p[8];
      int spins = 0;
      while (true) {
        bool ok = true;
        const int sc = ((++spins & 63) == 0);
#pragma unroll
        for (int m2 = 0; m2 < 8; ++m2) {
          p[m2] = sc
            ? __hip_atomic_fetch_add(src + lane * 8 + m2, z0, __ATOMIC_RELAXED,
                                     __HIP_MEMORY_SCOPE_AGENT)
            : __hip_atomic_fetch_add(src + lane * 8 + m2, z0, __ATOMIC_RELAXED,
                                     __HIP_MEMORY_SCOPE_WORKGROUP);
          ok &= ((unsigned)(p[m2] >> 32) == (unsigned)T_STEPS);
        }
        if (__all(ok)) break;
      }
#pragma unroll
      for (int m2 = 0; m2 < 8; ++m2) hv[m2] = __uint_as_float((unsigned)p[m2]);
    }
    float mx = hv[0];
#pragma unroll
    for (int m2 = 1; m2 < 8; ++m2) mx = fmaxf(mx, hv[m2]);
    mx = fmaxf(mx, __shfl_xor(mx, 1));
    mx = fmaxf(mx, __shfl_xor(mx, 2));
    mx = fmaxf(mx, __shfl_xor(mx, 4));
    mx = fmaxf(mx, __shfl_xor(mx, 8));
    mx = fmaxf(mx, __shfl_xor(mx, 16));
    mx = fmaxf(mx, __shfl_xor(mx, 32));
    float ex[8], sum = 0.f;
#pragma unroll
    for (int m2 = 0; m2 < 8; ++m2) { ex[m2] = expf(hv[m2] - mx); sum += ex[m2]; }
    sum += __shfl_xor(sum, 1);
    sum += __shfl_xor(sum, 2);
    sum += __shfl_xor(sum, 4);
    sum += __shfl_xor(sum, 8);
    sum += __shfl_xor(sum, 16);
    sum += __shfl_xor(sum, 32);
    float inv = 1.f / sum;
#pragma unroll
    for (int m2 = 0; m2 < 8; ++m2) out[lane * 8 + m2] = ex[m2] * inv;
  }
}

extern "C" void kernel_launch(void* const* d_in, const int* in_sizes, int n_in,
                              void* d_out, int out_size, void* d_ws, size_t ws_size,
                              hipStream_t stream) {
  const float* x   = (const float*)d_in[0];
  const float* Wih = (const float*)d_in[1];
  const float* Whh = (const float*)d_in[2];
  const float* bih = (const float*)d_in[3];
  const float* bhh = (const float*)d_in[4];
  float* out = (float*)d_out;
  unsigned long long* hbuf = (unsigned long long*)d_ws;   // 8 KB
  int* elect = (int*)((char*)d_ws + 8192);                // 8 ctrs + winner

  (void)hipMemsetAsync(d_ws, 0, 8192 + 64, stream);  // zero tags+election (capture-safe)
  lstm_l2rmw<<<NLAUNCH, WGSIZE, 0, stream>>>(x, Wih, Whh, bih, bhh, out,
                                             hbuf, elect);
}

// Round 13
// 105516.272 us; speedup vs baseline: 3.9749x; 3.9749x over previous
//
#include <hip/hip_runtime.h>
#include <math.h>

#define T_STEPS 65536
#define HID     512
#define NWG     64
#define WGSIZE  256

typedef float        f2v   __attribute__((ext_vector_type(2)));
typedef unsigned int uint4v __attribute__((ext_vector_type(4)));

// R11 skeleton (agent-atomic tagged mailbox, 1 barrier/step, 2-deep x reg
// prefetch, pinned weights, 4-acc dot, exp2/rcp gates, ds_swizzle gathers)
// + R13: depth-2 software-pipelined 16B LIC polls (detect granularity
// ~0.5 RT instead of ~1.5 RT). Poll loop entered with 0 outstanding VMEM
// (x staged first), so vmcnt(1) arithmetic is exact.
//
// Layout per workgroup (256 thr = 4 waves):
//   WG owns 8 h-indices: [wg*8, wg*8+8).
//   lane = r + 8*g: r -> (jloc=r&1, gate=r>>1) (PyTorch i,f,g,o), g = k-group.
//   Each lane holds 64 fp32 of W_hh and 64 of W_ih (asm-pinned).

__global__ __launch_bounds__(WGSIZE, 1)
void lstm_persistent(const float* __restrict__ x,      // [T,512]
                     const float* __restrict__ Wih,    // [2048,512]
                     const float* __restrict__ Whh,    // [2048,512]
                     const float* __restrict__ bih,    // [2048]
                     const float* __restrict__ bhh,    // [2048]
                     float* __restrict__ out,          // [512]
                     unsigned long long* hbuf)         // [2][512] tagged pairs
{
  const int wg   = blockIdx.x;
  const int tid  = threadIdx.x;
  const int wid  = tid >> 6;
  const int lane = tid & 63;
  const int r    = lane & 7;
  const int g    = lane >> 3;
  const int k0   = g << 6;            // 64-float k-slice start
  const int jloc = r & 1;
  const int gate = r >> 1;            // 0=i 1=f 2=g 3=o
  const int hidx = wg * 8 + wid * 2 + jloc;
  const int row  = gate * HID + hidx;

  __shared__ __align__(16) float hl[2][512];
  __shared__ __align__(16) float xl[2][512];

  // ---- load weights into registers (static indices only) ----
  float whh[64], wih[64];
#pragma unroll
  for (int i = 0; i < 16; ++i) {
    const int kk = k0 + (((i + g) & 15) << 2);
    float4 a = *reinterpret_cast<const float4*>(Whh + (size_t)row * 512 + kk);
    float4 b = *reinterpret_cast<const float4*>(Wih + (size_t)row * 512 + kk);
    whh[4*i+0] = a.x; whh[4*i+1] = a.y; whh[4*i+2] = a.z; whh[4*i+3] = a.w;
    wih[4*i+0] = b.x; wih[4*i+1] = b.y; wih[4*i+2] = b.z; wih[4*i+3] = b.w;
  }
  float bias = bih[row] + bhh[row];

  // ---- pin weight values (no in-loop rematerialization) ----
#pragma unroll
  for (int i = 0; i < 64; ++i) {
    asm volatile("" : "+v"(whh[i]));
    asm volatile("" : "+v"(wih[i]));
  }
  asm volatile("" : "+v"(bias));

  // ---- stage x_0; prefetch x_1 into registers ----
  if (tid < 128) {
    float4 v = reinterpret_cast<const float4*>(x)[tid];
    *reinterpret_cast<float4*>(&xl[0][tid * 4]) = v;
  }
  float4 xv;
  if (tid < 128) xv = reinterpret_cast<const float4*>(x + (size_t)512)[tid];
  __syncthreads();

  // 4 rotating accumulators: FMA dep chain 16 instead of 64.
  auto dot_lds = [&](const float* lds, const float* w) -> float {
    float a0 = 0.f, a1 = 0.f, a2 = 0.f, a3 = 0.f;
#pragma unroll
    for (int i = 0; i < 16; ++i) {
      const int kk = k0 + (((i + g) & 15) << 2);
      float4 v = *reinterpret_cast<const float4*>(lds + kk);
      a0 = fmaf(w[4*i+0], v.x, a0);
      a1 = fmaf(w[4*i+1], v.y, a1);
      a2 = fmaf(w[4*i+2], v.z, a2);
      a3 = fmaf(w[4*i+3], v.w, a3);
    }
    return (a0 + a1) + (a2 + a3);
  };

  const float LOG2E  = 1.4426950408889634f;
  const float LOG2E2 = 2.8853900817779268f;

  float xacc = dot_lds(xl[0], wih);   // x-projection partial for t=0
  float c    = 0.f;

#pragma unroll 1
  for (int t = 0; t < T_STEPS; ++t) {
    // ======== staging region ========
    // x FIRST: consuming xv forces the compiler's vmcnt drain of the x load
    // (and overlaps the post's store-ack) BEFORE the poll loop -> poll enters
    // with 0 outstanding VMEM and vmcnt(1) below is exact.
    if ((tid < 128) && (t + 1 < T_STEPS))
      *reinterpret_cast<float4*>(&xl[(t + 1) & 1][tid * 4]) = xv;   // xv = x_{t+1}

    if (t > 0) {
      const unsigned long long* src = hbuf + (((t - 1) & 1) << 9) + (tid << 1);
      const unsigned exp = (unsigned)t;
      uint4v pa, pb;
      unsigned h0, h1;
      // depth-2 pipelined 16B LIC polls (sc0 sc1 = device level, proven R2 path)
      asm volatile("global_load_dwordx4 %0, %1, off sc0 sc1"
                   : "=&v"(pa) : "v"(src) : "memory");
      asm volatile("global_load_dwordx4 %0, %1, off sc0 sc1"
                   : "=&v"(pb) : "v"(src) : "memory");
      while (true) {
        asm volatile("s_waitcnt vmcnt(1)" ::: "memory");   // oldest (pa) done
        __builtin_amdgcn_sched_barrier(0);
        if (pa.y == exp && pa.w == exp) { h0 = pa.x; h1 = pa.z; break; }
        asm volatile("global_load_dwordx4 %0, %1, off sc0 sc1"
                     : "=&v"(pa) : "v"(src) : "memory");
        asm volatile("s_waitcnt vmcnt(1)" ::: "memory");   // oldest (pb) done
        __builtin_amdgcn_sched_barrier(0);
        if (pb.y == exp && pb.w == exp) { h0 = pb.x; h1 = pb.z; break; }
        asm volatile("global_load_dwordx4 %0, %1, off sc0 sc1"
                     : "=&v"(pb) : "v"(src) : "memory");
      }
      // drain the still-in-flight poll, and keep pa/pb alive until it lands
      asm volatile("s_waitcnt vmcnt(0)" ::: "memory");
      asm volatile("" :: "v"(pa), "v"(pb));

      f2v hv;
      hv.x = __uint_as_float(h0);
      hv.y = __uint_as_float(h1);
      *reinterpret_cast<f2v*>(&hl[t & 1][tid << 1]) = hv;   // one 8B ds_write
    }
    __syncthreads();   // single barrier per step

    // ======== compute region ========
    if ((tid < 128) && (t + 2 < T_STEPS))
      xv = reinterpret_cast<const float4*>(x + (size_t)(t + 2) * 512)[tid];

    float acc = xacc;
    if (t > 0) acc += dot_lds(hl[t & 1], whh);
    // reduce over 8 k-groups: xor 8,16 via ds_swizzle, xor 32 via shfl
    acc += __int_as_float(__builtin_amdgcn_ds_swizzle(__float_as_int(acc), 0x201F));
    acc += __int_as_float(__builtin_amdgcn_ds_swizzle(__float_as_int(acc), 0x401F));
    acc += __shfl_xor(acc, 32);
    acc += bias;

    // sigmoid for i,f,o; tanh (=2*sig(2x)-1) for g — exp2 + rcp fast path
    const bool isg = (gate == 2);
    float xs = isg ? 2.f * acc : acc;
    float s  = __builtin_amdgcn_rcpf(1.f + exp2f(-xs * LOG2E));
    float v  = isg ? (2.f * s - 1.f) : s;

    // gather i,f,g,o for my jloc: static swizzle, src = (lane&0x19)|(gate<<1)
    const int vb = __float_as_int(v);
    float iv = __int_as_float(__builtin_amdgcn_ds_swizzle(vb, 0x019));
    float fv = __int_as_float(__builtin_amdgcn_ds_swizzle(vb, 0x059));
    float gv = __int_as_float(__builtin_amdgcn_ds_swizzle(vb, 0x099));
    float ov = __int_as_float(__builtin_amdgcn_ds_swizzle(vb, 0x0D9));

    c = fv * c + iv * gv;
    float th = 2.f * __builtin_amdgcn_rcpf(1.f + exp2f(-LOG2E2 * c)) - 1.f;
    float hn = ov * th;

    // post tagged h_t (lanes 0,1 of every wave): fire-and-forget agent atomic
    if (lane < 2) {
      unsigned long long pk =
          ((unsigned long long)(unsigned)(t + 1) << 32) | (unsigned)__float_as_uint(hn);
      __hip_atomic_store(hbuf + ((t & 1) << 9) + wg * 8 + wid * 2 + lane, pk,
                         __ATOMIC_RELAXED, __HIP_MEMORY_SCOPE_AGENT);
    }

    // x-projection partial for t+1 (off critical path; hides post landing)
    if (t + 1 < T_STEPS) xacc = dot_lds(xl[(t + 1) & 1], wih);
  }

  // ---- softmax(h_{T-1}) by wg 0, wave 0 (precision-path expf kept) ----
  if (wg == 0 && wid == 0) {
    const unsigned long long* src = hbuf + (((T_STEPS - 1) & 1) << 9);
    float hv[8];
    {
      unsigned long long p[8];
      while (true) {
        bool ok = true;
#pragma unroll
        for (int m2 = 0; m2 < 8; ++m2) {
          p[m2] = __hip_atomic_load(src + lane * 8 + m2,
                                    __ATOMIC_RELAXED, __HIP_MEMORY_SCOPE_AGENT);
          ok &= ((unsigned)(p[m2] >> 32) == (unsigned)T_STEPS);
        }
        if (__all(ok)) break;
      }
#pragma unroll
      for (int m2 = 0; m2 < 8; ++m2) hv[m2] = __uint_as_float((unsigned)p[m2]);
    }
    float mx = hv[0];
#pragma unroll
    for (int m2 = 1; m2 < 8; ++m2) mx = fmaxf(mx, hv[m2]);
    mx = fmaxf(mx, __shfl_xor(mx, 1));
    mx = fmaxf(mx, __shfl_xor(mx, 2));
    mx = fmaxf(mx, __shfl_xor(mx, 4));
    mx = fmaxf(mx, __shfl_xor(mx, 8));
    mx = fmaxf(mx, __shfl_xor(mx, 16));
    mx = fmaxf(mx, __shfl_xor(mx, 32));
    float ex[8], sum = 0.f;
#pragma unroll
    for (int m2 = 0; m2 < 8; ++m2) { ex[m2] = expf(hv[m2] - mx); sum += ex[m2]; }
    sum += __shfl_xor(sum, 1);
    sum += __shfl_xor(sum, 2);
    sum += __shfl_xor(sum, 4);
    sum += __shfl_xor(sum, 8);
    sum += __shfl_xor(sum, 16);
    sum += __shfl_xor(sum, 32);
    float inv = 1.f / sum;
#pragma unroll
    for (int m2 = 0; m2 < 8; ++m2) out[lane * 8 + m2] = ex[m2] * inv;
  }
}

extern "C" void kernel_launch(void* const* d_in, const int* in_sizes, int n_in,
                              void* d_out, int out_size, void* d_ws, size_t ws_size,
                              hipStream_t stream) {
  const float* x   = (const float*)d_in[0];
  const float* Wih = (const float*)d_in[1];
  const float* Whh = (const float*)d_in[2];
  const float* bih = (const float*)d_in[3];
  const float* bhh = (const float*)d_in[4];
  float* out = (float*)d_out;
  unsigned long long* hbuf = (unsigned long long*)d_ws;  // 2 x 512 x 8B = 8 KB

  (void)hipMemsetAsync(d_ws, 0, 8192, stream);  // zero tags each launch (capture-safe)
  lstm_persistent<<<NWG, WGSIZE, 0, stream>>>(x, Wih, Whh, bih, bhh, out, hbuf);
}

// Round 14
// 98837.830 us; speedup vs baseline: 4.2435x; 1.0676x over previous
//
#include <hip/hip_runtime.h>
#include <math.h>

#define T_STEPS 65536
#define HID     512
#define NWG     64
#define WGSIZE  256

typedef float        f2v    __attribute__((ext_vector_type(2)));
typedef unsigned int uint4v __attribute__((ext_vector_type(4)));

// R11 skeleton (agent-atomic tagged mailbox, 1 barrier/step, 2-deep x reg
// prefetch, pinned weights, 4-acc dot, exp2/rcp gates, ds_swizzle gathers)
// + R14: depth-4 ROTATING same-address poll ring. Unlike R13's pair (which
// re-synchronized and sampled at RT granularity), a 4-slot ring with one
// {wait vmcnt(3); check oldest; reissue} per step reaches steady-state issue
// spacing of RT/4 -> detect lag ~ RT + RT/8 instead of ~1.5 RT.
// Poll loop is entered with 0 outstanding VMEM (x staged first), so the
// vmcnt ring arithmetic is exact.
//
// Layout per workgroup (256 thr = 4 waves):
//   WG owns 8 h-indices: [wg*8, wg*8+8).
//   lane = r + 8*g: r -> (jloc=r&1, gate=r>>1) (PyTorch i,f,g,o), g = k-group.
//   Each lane holds 64 fp32 of W_hh and 64 of W_ih (asm-pinned).

__global__ __launch_bounds__(WGSIZE, 1)
void lstm_persistent(const float* __restrict__ x,      // [T,512]
                     const float* __restrict__ Wih,    // [2048,512]
                     const float* __restrict__ Whh,    // [2048,512]
                     const float* __restrict__ bih,    // [2048]
                     const float* __restrict__ bhh,    // [2048]
                     float* __restrict__ out,          // [512]
                     unsigned long long* hbuf)         // [2][512] tagged pairs
{
  const int wg   = blockIdx.x;
  const int tid  = threadIdx.x;
  const int wid  = tid >> 6;
  const int lane = tid & 63;
  const int r    = lane & 7;
  const int g    = lane >> 3;
  const int k0   = g << 6;            // 64-float k-slice start
  const int jloc = r & 1;
  const int gate = r >> 1;            // 0=i 1=f 2=g 3=o
  const int hidx = wg * 8 + wid * 2 + jloc;
  const int row  = gate * HID + hidx;

  __shared__ __align__(16) float hl[2][512];
  __shared__ __align__(16) float xl[2][512];

  // ---- load weights into registers (static indices only) ----
  float whh[64], wih[64];
#pragma unroll
  for (int i = 0; i < 16; ++i) {
    const int kk = k0 + (((i + g) & 15) << 2);
    float4 a = *reinterpret_cast<const float4*>(Whh + (size_t)row * 512 + kk);
    float4 b = *reinterpret_cast<const float4*>(Wih + (size_t)row * 512 + kk);
    whh[4*i+0] = a.x; whh[4*i+1] = a.y; whh[4*i+2] = a.z; whh[4*i+3] = a.w;
    wih[4*i+0] = b.x; wih[4*i+1] = b.y; wih[4*i+2] = b.z; wih[4*i+3] = b.w;
  }
  float bias = bih[row] + bhh[row];

  // ---- pin weight values (no in-loop rematerialization) ----
#pragma unroll
  for (int i = 0; i < 64; ++i) {
    asm volatile("" : "+v"(whh[i]));
    asm volatile("" : "+v"(wih[i]));
  }
  asm volatile("" : "+v"(bias));

  // ---- stage x_0; prefetch x_1 into registers ----
  if (tid < 128) {
    float4 v = reinterpret_cast<const float4*>(x)[tid];
    *reinterpret_cast<float4*>(&xl[0][tid * 4]) = v;
  }
  float4 xv;
  if (tid < 128) xv = reinterpret_cast<const float4*>(x + (size_t)512)[tid];
  __syncthreads();

  // 4 rotating accumulators: FMA dep chain 16 instead of 64.
  auto dot_lds = [&](const float* lds, const float* w) -> float {
    float a0 = 0.f, a1 = 0.f, a2 = 0.f, a3 = 0.f;
#pragma unroll
    for (int i = 0; i < 16; ++i) {
      const int kk = k0 + (((i + g) & 15) << 2);
      float4 v = *reinterpret_cast<const float4*>(lds + kk);
      a0 = fmaf(w[4*i+0], v.x, a0);
      a1 = fmaf(w[4*i+1], v.y, a1);
      a2 = fmaf(w[4*i+2], v.z, a2);
      a3 = fmaf(w[4*i+3], v.w, a3);
    }
    return (a0 + a1) + (a2 + a3);
  };

  const float LOG2E  = 1.4426950408889634f;
  const float LOG2E2 = 2.8853900817779268f;

  float xacc = dot_lds(xl[0], wih);   // x-projection partial for t=0
  float c    = 0.f;

#pragma unroll 1
  for (int t = 0; t < T_STEPS; ++t) {
    // ======== staging region ========
    // x FIRST: consuming xv forces the vmcnt drain of the x load (and the
    // post's ack) BEFORE the poll ring -> ring enters with 0 outstanding.
    if ((tid < 128) && (t + 1 < T_STEPS))
      *reinterpret_cast<float4*>(&xl[(t + 1) & 1][tid * 4]) = xv;   // xv = x_{t+1}

    if (t > 0) {
      const unsigned long long* src = hbuf + (((t - 1) & 1) << 9) + (tid << 1);
      const unsigned exp = (unsigned)t;
      uint4v q0, q1, q2, q3;
      unsigned h0, h1;
#define POLL_ISSUE(Q) \
      asm volatile("global_load_dwordx4 %0, %1, off sc0 sc1" \
                   : "=&v"(Q) : "v"(src) : "memory")
      POLL_ISSUE(q0); POLL_ISSUE(q1); POLL_ISSUE(q2); POLL_ISSUE(q3);
      while (true) {
        asm volatile("s_waitcnt vmcnt(3)" ::: "memory");   // oldest = q0
        __builtin_amdgcn_sched_barrier(0);
        if (q0.y == exp && q0.w == exp) { h0 = q0.x; h1 = q0.z; break; }
        POLL_ISSUE(q0);
        asm volatile("s_waitcnt vmcnt(3)" ::: "memory");   // oldest = q1
        __builtin_amdgcn_sched_barrier(0);
        if (q1.y == exp && q1.w == exp) { h0 = q1.x; h1 = q1.z; break; }
        POLL_ISSUE(q1);
        asm volatile("s_waitcnt vmcnt(3)" ::: "memory");   // oldest = q2
        __builtin_amdgcn_sched_barrier(0);
        if (q2.y == exp && q2.w == exp) { h0 = q2.x; h1 = q2.z; break; }
        POLL_ISSUE(q2);
        asm volatile("s_waitcnt vmcnt(3)" ::: "memory");   // oldest = q3
        __builtin_amdgcn_sched_barrier(0);
        if (q3.y == exp && q3.w == exp) { h0 = q3.x; h1 = q3.z; break; }
        POLL_ISSUE(q3);
      }
#undef POLL_ISSUE
      // drain in-flight ring loads; keep ring regs alive until they land
      asm volatile("s_waitcnt vmcnt(0)" ::: "memory");
      asm volatile("" :: "v"(q0), "v"(q1), "v"(q2), "v"(q3));

      f2v hv;
      hv.x = __uint_as_float(h0);
      hv.y = __uint_as_float(h1);
      *reinterpret_cast<f2v*>(&hl[t & 1][tid << 1]) = hv;   // one 8B ds_write
    }
    __syncthreads();   // single barrier per step

    // ======== compute region ========
    if ((tid < 128) && (t + 2 < T_STEPS))
      xv = reinterpret_cast<const float4*>(x + (size_t)(t + 2) * 512)[tid];

    float acc = xacc;
    if (t > 0) acc += dot_lds(hl[t & 1], whh);
    // reduce over 8 k-groups: xor 8,16 via ds_swizzle, xor 32 via shfl
    acc += __int_as_float(__builtin_amdgcn_ds_swizzle(__float_as_int(acc), 0x201F));
    acc += __int_as_float(__builtin_amdgcn_ds_swizzle(__float_as_int(acc), 0x401F));
    acc += __shfl_xor(acc, 32);
    acc += bias;

    // sigmoid for i,f,o; tanh (=2*sig(2x)-1) for g — exp2 + rcp fast path
    const bool isg = (gate == 2);
    float xs = isg ? 2.f * acc : acc;
    float s  = __builtin_amdgcn_rcpf(1.f + exp2f(-xs * LOG2E));
    float v  = isg ? (2.f * s - 1.f) : s;

    // gather i,f,g,o for my jloc: static swizzle, src = (lane&0x19)|(gate<<1)
    const int vb = __float_as_int(v);
    float iv = __int_as_float(__builtin_amdgcn_ds_swizzle(vb, 0x019));
    float fv = __int_as_float(__builtin_amdgcn_ds_swizzle(vb, 0x059));
    float gv = __int_as_float(__builtin_amdgcn_ds_swizzle(vb, 0x099));
    float ov = __int_as_float(__builtin_amdgcn_ds_swizzle(vb, 0x0D9));

    c = fv * c + iv * gv;
    float th = 2.f * __builtin_amdgcn_rcpf(1.f + exp2f(-LOG2E2 * c)) - 1.f;
    float hn = ov * th;

    // post tagged h_t (lanes 0,1 of every wave): fire-and-forget agent atomic
    if (lane < 2) {
      unsigned long long pk =
          ((unsigned long long)(unsigned)(t + 1) << 32) | (unsigned)__float_as_uint(hn);
      __hip_atomic_store(hbuf + ((t & 1) << 9) + wg * 8 + wid * 2 + lane, pk,
                         __ATOMIC_RELAXED, __HIP_MEMORY_SCOPE_AGENT);
    }

    // x-projection partial for t+1 (off critical path; hides post landing)
    if (t + 1 < T_STEPS) xacc = dot_lds(xl[(t + 1) & 1], wih);
  }

  // ---- softmax(h_{T-1}) by wg 0, wave 0 (precision-path expf kept) ----
  if (wg == 0 && wid == 0) {
    const unsigned long long* src = hbuf + (((T_STEPS - 1) & 1) << 9);
    float hv[8];
    {
      unsigned long long p[8];
      while (true) {
        bool ok = true;
#pragma unroll
        for (int m2 = 0; m2 < 8; ++m2) {
          p[m2] = __hip_atomic_load(src + lane * 8 + m2,
                                    __ATOMIC_RELAXED, __HIP_MEMORY_SCOPE_AGENT);
          ok &= ((unsigned)(p[m2] >> 32) == (unsigned)T_STEPS);
        }
        if (__all(ok)) break;
      }
#pragma unroll
      for (int m2 = 0; m2 < 8; ++m2) hv[m2] = __uint_as_float((unsigned)p[m2]);
    }
    float mx = hv[0];
#pragma unroll
    for (int m2 = 1; m2 < 8; ++m2) mx = fmaxf(mx, hv[m2]);
    mx = fmaxf(mx, __shfl_xor(mx, 1));
    mx = fmaxf(mx, __shfl_xor(mx, 2));
    mx = fmaxf(mx, __shfl_xor(mx, 4));
    mx = fmaxf(mx, __shfl_xor(mx, 8));
    mx = fmaxf(mx, __shfl_xor(mx, 16));
    mx = fmaxf(mx, __shfl_xor(mx, 32));
    float ex[8], sum = 0.f;
#pragma unroll
    for (int m2 = 0; m2 < 8; ++m2) { ex[m2] = expf(hv[m2] - mx); sum += ex[m2]; }
    sum += __shfl_xor(sum, 1);
    sum += __shfl_xor(sum, 2);
    sum += __shfl_xor(sum, 4);
    sum += __shfl_xor(sum, 8);
    sum += __shfl_xor(sum, 16);
    sum += __shfl_xor(sum, 32);
    float inv = 1.f / sum;
#pragma unroll
    for (int m2 = 0; m2 < 8; ++m2) out[lane * 8 + m2] = ex[m2] * inv;
  }
}

extern "C" void kernel_launch(void* const* d_in, const int* in_sizes, int n_in,
                              void* d_out, int out_size, void* d_ws, size_t ws_size,
                              hipStream_t stream) {
  const float* x   = (const float*)d_in[0];
  const float* Wih = (const float*)d_in[1];
  const float* Whh = (const float*)d_in[2];
  const float* bih = (const float*)d_in[3];
  const float* bhh = (const float*)d_in[4];
  float* out = (float*)d_out;
  unsigned long long* hbuf = (unsigned long long*)d_ws;  // 2 x 512 x 8B = 8 KB

  (void)hipMemsetAsync(d_ws, 0, 8192, stream);  // zero tags each launch (capture-safe)
  lstm_persistent<<<NWG, WGSIZE, 0, stream>>>(x, Wih, Whh, bih, bhh, out, hbuf);
}